// Round 1
// baseline (14822.452 us; speedup 1.0000x reference)
//
#include <hip/hip_runtime.h>
#include <hip/hip_cooperative_groups.h>
#include <math.h>

namespace cg = cooperative_groups;

#define HH 512   // hidden
#define DD 512   // embed dim
#define BB 64    // batch (== one wave)
#define SS 256   // seq len
#define KK 1024  // D+H
#define CC 5

// ---------------------------------------------------------------------------
// Gather embeddings, transposed to [s][d][b] so recurrence loads are coalesced
// along b (64 lanes = 64 batch elems = one 256B segment per k).
// ---------------------------------------------------------------------------
__global__ __launch_bounds__(256)
void gather_embed_k(const int* __restrict__ x, const float* __restrict__ embed,
                    float* __restrict__ xeT)
{
    const int s   = blockIdx.x;
    const int tid = threadIdx.x;
    const int b   = tid & 63;
    const int grp = tid >> 6;
    __shared__ int rows[BB];
    if (tid < BB) rows[tid] = x[tid * SS + s];   // x is [B][S]
    __syncthreads();
    const float* e = embed + (size_t)rows[b] * DD;
    float* o = xeT + (size_t)s * DD * BB + b;
    for (int d = grp * 128; d < grp * 128 + 128; ++d)
        o[(size_t)d * BB] = e[d];                // coalesced writes along b
}

__device__ __forceinline__ float sigmoidf_(float v) {
    return 1.0f / (1.0f + expf(-v));
}

// ---------------------------------------------------------------------------
// Cooperative recurrence. 256 WGs x 256 threads.
//   WG w: dir = w>>7, owns 4 h-values [h0, h0+4) -> 16 gate rows (4 gates x 4 h).
//   Wave r (0..3): K-quarter. r<2: x-part halves, r>=2: h-part halves.
//   Lane = batch element. Weights read via wave-uniform addresses (s_load).
//   One grid.sync() per timestep; h double-buffered by phase t&1.
// ---------------------------------------------------------------------------
__global__ __launch_bounds__(256)
void bilstm_recur_k(const float* __restrict__ xeT,
                    const float* __restrict__ fwd_W, const float* __restrict__ fwd_b,
                    const float* __restrict__ bwd_W, const float* __restrict__ bwd_b,
                    float* __restrict__ hbuf,   // [phase 2][dir 2][H][B]
                    float* __restrict__ hist)   // [dir 2][S][H][B]
{
    cg::grid_group grid = cg::this_grid();
    const int w     = blockIdx.x;
    const int dir   = w >> 7;
    const int slice = w & 127;
    const int h0    = slice << 2;          // 4 h-values per WG
    const int tid   = threadIdx.x;
    const int b     = tid & 63;
    const int r     = __builtin_amdgcn_readfirstlane(tid >> 6);

    const float* W  = dir ? bwd_W : fwd_W;
    const float* bi = dir ? bwd_b : fwd_b;

    const int isH  = r >> 1;               // 0: x columns, 1: h columns
    const int k0   = (r & 1) * 256;        // which half of that 512-range
    const int woff = isH * DD + k0;        // offset into the K=1024 weight row

    // base for wave-uniform weight reads: W[(g*H + h0+hh)*KK + woff + k]
    //   = wbase[g*(HH*KK) + hh*KK + k]  (g,hh unrolled -> constant offsets)
    const float* wbase = W + (size_t)h0 * KK + woff;

    __shared__ float part[4][16][BB];      // per-wave partial preacts

    // zero h(t=0), phase 0: each WG zeroes its own 4h x 64b slice
    hbuf[((size_t)(0 * 2 + dir) * HH + h0 + (tid >> 6)) * BB + b] = 0.0f;
    grid.sync();

    for (int t = 0; t < SS; ++t) {
        const int s = dir ? (SS - 1 - t) : t;
        const float* col = isH ? (hbuf + (size_t)((t & 1) * 2 + dir) * HH * BB)
                               : (xeT + (size_t)s * DD * BB);
        const float* cb = col + (size_t)k0 * BB + b;

        float acc[16];
        #pragma unroll
        for (int i = 0; i < 16; ++i) acc[i] = 0.0f;

        #pragma unroll 4
        for (int k = 0; k < 256; ++k) {
            const float v = cb[(size_t)k * BB];        // coalesced, lanes = b
            #pragma unroll
            for (int g = 0; g < 4; ++g) {
                #pragma unroll
                for (int hh = 0; hh < 4; ++hh) {
                    acc[g * 4 + hh] = fmaf(v, wbase[(size_t)g * (HH * KK) + hh * KK + k],
                                           acc[g * 4 + hh]);
                }
            }
        }

        #pragma unroll
        for (int i = 0; i < 16; ++i) part[r][i][b] = acc[i];
        __syncthreads();

        // combine: thread -> (hh = tid>>6, b); sum 4 wave partials + bias
        {
            const int hh = tid >> 6;
            float pg[4];
            #pragma unroll
            for (int g = 0; g < 4; ++g) {
                const int row = g * 4 + hh;
                pg[g] = part[0][row][b] + part[1][row][b] +
                        part[2][row][b] + part[3][row][b] +
                        bi[g * HH + h0 + hh];
            }
            const float f  = sigmoidf_(pg[0]);
            const float i_ = sigmoidf_(pg[1]);
            const float ct = tanhf(pg[2]);
            const float o  = sigmoidf_(pg[3]);
            const float c  = (f + i_) * ct;   // faithful: prev cell state unused
            const float hn = o * tanhf(c);
            const int h = h0 + hh;
            hbuf[((size_t)(((t & 1) ^ 1) * 2 + dir) * HH + h) * BB + b] = hn;
            hist[(((size_t)dir * SS + s) * HH + h) * BB + b] = hn;
        }
        grid.sync();
    }
}

// ---------------------------------------------------------------------------
// pooled[h][b] = max_s tanh(hf[s][h][b] * hb[s][h][b])
// ---------------------------------------------------------------------------
__global__ __launch_bounds__(256)
void pool_k(const float* __restrict__ hist, float* __restrict__ pooled)
{
    const int i = blockIdx.x * 256 + threadIdx.x;  // i = h*64 + b, 0..32767
    float m = -2.0f;
    for (int s = 0; s < SS; ++s) {
        const float a = hist[(size_t)s * (HH * BB) + i];
        const float c = hist[(size_t)(SS + s) * (HH * BB) + i];
        m = fmaxf(m, tanhf(a * c));
    }
    pooled[i] = m;
}

// ---------------------------------------------------------------------------
// out[b][c] = sum_h pooled[h][b] * Wout[c][h] + bout[c]
// ---------------------------------------------------------------------------
__global__ __launch_bounds__(256)
void outgemm_k(const float* __restrict__ pooled, const float* __restrict__ Wout,
               const float* __restrict__ bout, float* __restrict__ out)
{
    const int c   = blockIdx.x;
    const int tid = threadIdx.x;
    const int b   = tid & 63;
    const int q   = __builtin_amdgcn_readfirstlane(tid >> 6);
    float p = 0.0f;
    for (int j = 0; j < 128; ++j) {
        const int h = q * 128 + j;
        p = fmaf(pooled[(size_t)h * BB + b], Wout[c * HH + h], p);
    }
    __shared__ float red[4][BB];
    red[q][b] = p;
    __syncthreads();
    if (tid < BB)
        out[tid * CC + c] = red[0][tid] + red[1][tid] + red[2][tid] + red[3][tid] + bout[c];
}

// ---------------------------------------------------------------------------
extern "C" void kernel_launch(void* const* d_in, const int* in_sizes, int n_in,
                              void* d_out, int out_size, void* d_ws, size_t ws_size,
                              hipStream_t stream)
{
    const int*   x     = (const int*)d_in[0];
    const float* embed = (const float*)d_in[1];
    const float* fwd_W = (const float*)d_in[2];
    const float* fwd_b = (const float*)d_in[3];
    const float* bwd_W = (const float*)d_in[4];
    const float* bwd_b = (const float*)d_in[5];
    const float* Wout  = (const float*)d_in[6];
    const float* bout  = (const float*)d_in[7];
    float* out = (float*)d_out;

    // workspace carve-up (floats): total ~25.3M floats ~= 101.3 MB
    float* ws     = (float*)d_ws;
    float* xeT    = ws;                                  // S*D*B   = 8,388,608
    float* hist   = xeT  + (size_t)SS * DD * BB;         // 2*S*H*B = 16,777,216
    float* hbuf   = hist + (size_t)2 * SS * HH * BB;     // 2*2*H*B = 131,072
    float* pooled = hbuf + (size_t)2 * 2 * HH * BB;      // H*B     = 32,768

    gather_embed_k<<<SS, 256, 0, stream>>>(x, embed, xeT);

    void* args[] = {(void*)&xeT, (void*)&fwd_W, (void*)&fwd_b, (void*)&bwd_W,
                    (void*)&bwd_b, (void*)&hbuf, (void*)&hist};
    hipLaunchCooperativeKernel((void*)bilstm_recur_k, dim3(256), dim3(256),
                               args, 0, stream);

    pool_k<<<128, 256, 0, stream>>>(hist, pooled);
    outgemm_k<<<CC, 256, 0, stream>>>(pooled, Wout, bout, out);
}